// Round 10
// baseline (86.204 us; speedup 1.0000x reference)
//
#include <hip/hip_runtime.h>
#include <math.h>

#define LOG2E 1.4426950408889634f

typedef __attribute__((ext_vector_type(8))) short short8;   // 8 bf16 (4 VGPR)
typedef __attribute__((ext_vector_type(4))) float f32x4;    // MFMA C/D
typedef __attribute__((ext_vector_type(2))) float f32x2;    // packed-f32 pair

__device__ __forceinline__ float fexp2(float x) { return __builtin_amdgcn_exp2f(x); }

// async global->LDS, 16B/lane: LDS dest = wave-uniform base + lane*16;
// global source per-lane. offset immediate ALWAYS 0 (R9 post-mortem: the
// offset=128 variant is the prime suspect for misaligned LDS writes --
// R7/R8's proven pattern is explicit pointer arithmetic + offset 0).
typedef __attribute__((address_space(1))) const unsigned int gas_u32;
typedef __attribute__((address_space(3))) unsigned int las_u32;
__device__ __forceinline__ void glds16(const uint4* g, uint4* l)
{ __builtin_amdgcn_global_load_lds((gas_u32*)g, (las_u32*)l, 16, 0, 0); }

// 21 Gaussian kernels for 2 sims -> acc[21] (f32x2), DEFERRED normalization
// (validated R6-R8): g_{9+j}(s) = gc * v^j * e^{-j^2/2}, v = e^{10s+0.5},
// gc = e^{-50(s+0.05)^2}. Accumulate p_j = gc*v^j; apply c_j at the fold.
// Overflow-safe with |s|<=1.1: max intermediate e^49.
__device__ __forceinline__ void kern21(f32x2 s, f32x2* acc)
{
    s.x = __builtin_amdgcn_fmed3f(s.x, -1.1f, 1.1f);
    s.y = __builtin_amdgcn_fmed3f(s.y, -1.1f, 1.1f);

    f32x2 va = s * 14.426950408889634f + 0.7213475204444817f;  // log2(e)*(10s+0.5)
    f32x2 v, vi, gc;
    v.x  = fexp2(va.x);  v.y  = fexp2(va.y);
    vi.x = __builtin_amdgcn_rcpf(v.x);
    vi.y = __builtin_amdgcn_rcpf(v.y);
    f32x2 t9 = s + 0.05f;
    f32x2 ga = (t9 * t9) * -72.13475204444817f;                // -50/ln2
    gc.x = fexp2(ga.x);  gc.y = fexp2(ga.y);

    f32x2 p = gc;
    acc[9] += p;
    #pragma unroll
    for (int k = 10; k <= 19; ++k) { p *= v; acc[k] += p; }    // up: j=1..10
    f32x2 q = gc;
    #pragma unroll
    for (int k = 8; k >= 0; --k) { q *= vi; acc[k] += q; }     // down: j=1..9
    // exact kernel (mu=1, sigma=0.001): wave-uniform skip (~0.1% taken)
    if (__any(fmaxf(s.x, s.y) > 0.995f)) {
        f32x2 te = s - 1.0f;
        f32x2 ea = (te * te) * -721347.5204444817f;
        f32x2 ge; ge.x = fexp2(ea.x); ge.y = fexp2(ea.y);
        acc[20] += ge;
    }
}

// One doc tile step: 6 MFMAs (hi/lo 3-term split) + 2x kern21.
__device__ __forceinline__ void doc_step(
    short8 Ah0, short8 Ah1, short8 Al0, short8 Al1,
    short8 Bh0, short8 Bh1, short8 Bl0, short8 Bl1, f32x2* acc)
{
    f32x4 C = {0.f, 0.f, 0.f, 0.f};
    C = __builtin_amdgcn_mfma_f32_16x16x32_bf16(Ah0, Bh0, C, 0, 0, 0);
    C = __builtin_amdgcn_mfma_f32_16x16x32_bf16(Ah1, Bh1, C, 0, 0, 0);
    C = __builtin_amdgcn_mfma_f32_16x16x32_bf16(Ah0, Bl0, C, 0, 0, 0);
    C = __builtin_amdgcn_mfma_f32_16x16x32_bf16(Ah1, Bl1, C, 0, 0, 0);
    C = __builtin_amdgcn_mfma_f32_16x16x32_bf16(Al0, Bh0, C, 0, 0, 0);
    C = __builtin_amdgcn_mfma_f32_16x16x32_bf16(Al1, Bh1, C, 0, 0, 0);

    f32x2 a01 = {C[0], C[1]};
    f32x2 a23 = {C[2], C[3]};
    kern21(a01, acc);
    kern21(a23, acc);
}

// ---- prep: normalize + bf16 hi/lo split every vocab row into ws ----
// layout: wse[tok*16 + 0..7] = hi chunks, wse[tok*16 + 8..15] = lo chunks
__global__ __launch_bounds__(256) void knrm_prep_kernel(
    const float* __restrict__ emb, uint4* __restrict__ wse, int vocab)
{
    const int tid = threadIdx.x;
    const int row = blockIdx.x * 32 + (tid >> 3);
    const int cb  = tid & 7;
    if (row >= vocab) return;   // whole 8-lane group exits together

    const float* src = emb + (size_t)row * 50;
    float v[8];
    float ss = 0.f;
    #pragma unroll
    for (int p = 0; p < 4; ++p) {
        int e = cb * 8 + 2 * p;
        float2 t;
        if (e + 2 <= 50) t = *(const float2*)(src + e);
        else             t = make_float2(0.f, 0.f);
        v[2*p]   = t.x;
        v[2*p+1] = t.y;
        ss = fmaf(t.x, t.x, fmaf(t.y, t.y, ss));
    }
    ss += __shfl_xor(ss, 1, 64);
    ss += __shfl_xor(ss, 2, 64);
    ss += __shfl_xor(ss, 4, 64);
    float rn = __builtin_amdgcn_rsqf(ss);

    unsigned hw[4], lw[4];
    #pragma unroll
    for (int p = 0; p < 4; ++p) {
        float a = v[2*p]   * rn;
        float b = v[2*p+1] * rn;
        unsigned ha = __float_as_uint(a) & 0xFFFF0000u;
        unsigned hb = __float_as_uint(b) & 0xFFFF0000u;
        float la = a - __uint_as_float(ha);
        float lb = b - __uint_as_float(hb);
        hw[p] = (ha >> 16) | hb;
        lw[p] = (__float_as_uint(la) >> 16) | (__float_as_uint(lb) & 0xFFFF0000u);
    }
    wse[(size_t)row * 16 + cb]     = make_uint4(hw[0], hw[1], hw[2], hw[3]);
    wse[(size_t)row * 16 + 8 + cb] = make_uint4(lw[0], lw[1], lw[2], lw[3]);
}

__device__ __forceinline__ short8 frag_ld(const uint4* mat, int row, int chunk)
{
    return __builtin_bit_cast(short8, mat[row * 8 + (chunk ^ (row & 7))]);
}

// ==== main pass kernel (PRE): wave-private pipeline, NO main-loop barriers ====
// Block = (batch, pass, qtile): bx = b*4 + pass*2 + qtile. 4 waves; wave w
// owns doc quarter [w*128, w*128+128) in 8 chunks of 16 rows, staged into a
// PRIVATE 8KB LDS double-buffer via glds (linear dest + pre-swizzled source,
// rule #21; offset=0 everywhere). Sync is per-wave s_waitcnt vmcnt(0)
// (asm + sched_barrier fences, rule #18; pattern m201-validated) -- no
// __syncthreads until the fold. B-frags per-lane from global (R6-validated).
__global__ __launch_bounds__(256, 4) void knrm_pass_pre(
    const int* __restrict__ q1, const int* __restrict__ d1,
    const int* __restrict__ q2, const int* __restrict__ d2,
    const uint4* __restrict__ wse, const float* __restrict__ mlp_w,
    float* __restrict__ ws_partial)
{
    __shared__ uint4 dbuf[4][2][256];   // [wave][buf][hi 0..127 | lo 128..255]
    __shared__ float Swk[4][21][16];
    __shared__ float wred[4];

    const int tid   = threadIdx.x;
    const int bx    = blockIdx.x;          // b*4 + pass*2 + qtile
    const int b     = bx >> 2;
    const int pass  = (bx >> 1) & 1;
    const int qtile = bx & 1;
    const int lane  = tid & 63;
    const int wave  = tid >> 6;
    const int g     = lane >> 4;           // k-group 0..3

    const int* qidx = (pass ? q2 : q1) + b * 32;
    const int* didx = (pass ? d2 : d1) + b * 512 + wave * 128;

    // ---- B fragments direct from global (once) ----
    const int qrow = qtile * 16 + (lane & 15);
    const uint4* qb = wse + (size_t)qidx[qrow] * 16;
    short8 Bh0 = __builtin_bit_cast(short8, qb[g]);
    short8 Bh1 = __builtin_bit_cast(short8, qb[4 + g]);
    short8 Bl0 = __builtin_bit_cast(short8, qb[8 + g]);
    short8 Bl1 = __builtin_bit_cast(short8, qb[12 + g]);

    const int rsel = lane >> 3;            // staging sub-row 0..7
    const int swz  = (lane & 7) ^ rsel;    // pre-swizzled source chunk

    // ---- prologue: chunk 0 -> buf0; tokens for chunk 1 ----
    int tokA = didx[rsel];                 // rows 0..7
    int tokB = didx[8 + rsel];             // rows 8..15
    {
        const uint4* pA = wse + (size_t)tokA * 16;
        const uint4* pB = wse + (size_t)tokB * 16;
        uint4* nb = dbuf[wave][0];
        glds16(pA + swz,     nb);
        glds16(pB + swz,     nb + 64);
        glds16(pA + 8 + swz, nb + 128);
        glds16(pB + 8 + swz, nb + 192);
    }
    tokA = didx[16 + rsel];
    tokB = didx[24 + rsel];

    f32x2 acc2[21];
    #pragma unroll
    for (int k = 0; k < 21; ++k) acc2[k] = (f32x2){0.f, 0.f};

    const int ar = lane & 15;

    #pragma unroll 2
    for (int c = 0; c < 8; ++c) {
        // wait for this chunk's glds (wave-private; nothing else outstanding)
        asm volatile("s_waitcnt vmcnt(0)" ::: "memory");
        __builtin_amdgcn_sched_barrier(0);

        const uint4* hb = dbuf[wave][c & 1];
        const uint4* lb = hb + 128;
        short8 Ah0 = frag_ld(hb, ar, g);
        short8 Ah1 = frag_ld(hb, ar, 4 + g);
        short8 Al0 = frag_ld(lb, ar, g);
        short8 Al1 = frag_ld(lb, ar, 4 + g);
        __builtin_amdgcn_sched_barrier(0);

        // issue next chunk's staging into the other buffer (offset-0 glds)
        if (c < 7) {
            const uint4* pA = wse + (size_t)tokA * 16;
            const uint4* pB = wse + (size_t)tokB * 16;
            uint4* nb = dbuf[wave][(c + 1) & 1];
            glds16(pA + swz,     nb);
            glds16(pB + swz,     nb + 64);
            glds16(pA + 8 + swz, nb + 128);
            glds16(pB + 8 + swz, nb + 192);
            if (c < 6) {
                tokA = didx[(c + 2) * 16 + rsel];
                tokB = didx[(c + 2) * 16 + 8 + rsel];
            }
        }
        __builtin_amdgcn_sched_barrier(0);

        // compute current chunk (register-only; glds latency hides under it)
        doc_step(Ah0, Ah1, Al0, Al1, Bh0, Bh1, Bl0, Bl1, acc2);
    }

    // ---- fold packed pair, then the 4 doc-row groups of the wave ----
    float acc[21];
    #pragma unroll
    for (int k = 0; k < 21; ++k) {
        float v = acc2[k].x + acc2[k].y;
        v += __shfl_xor(v, 16, 64);
        v += __shfl_xor(v, 32, 64);
        acc[k] = v;
    }
    if (lane < 16) {
        #pragma unroll
        for (int k = 0; k < 21; ++k) Swk[wave][k][lane] = acc[k];
    }
    __syncthreads();

    // ---- log1p + deferred c_j scale + weights; sum over this block's 16 q ----
    float local = 0.f;
    for (int p = tid; p < 21 * 16; p += 256) {
        int k = p >> 4, q = p & 15;
        float S = Swk[0][k][q] + Swk[1][k][q] + Swk[2][k][q] + Swk[3][k][q];
        float j = (float)(k - 9);
        float scale = (k < 20) ? fexp2(-0.7213475204444817f * j * j) : 1.0f;
        local += mlp_w[k] * log1pf(S * scale);
    }
    #pragma unroll
    for (int off = 1; off < 64; off <<= 1) local += __shfl_xor(local, off, 64);
    if (lane == 0) wred[wave] = local;
    __syncthreads();
    if (tid == 0)
        ws_partial[bx] = wred[0] + wred[1] + wred[2] + wred[3];  // qtile partial
}

// ==== fallback (ws too small): R2-proven in-kernel staging via LDS ====
__device__ __forceinline__ void stage_row_chunk(
    const float* __restrict__ emb, int tok, int row, int cb,
    uint4* __restrict__ hmat, uint4* __restrict__ lmat)
{
    const float* src = emb + (size_t)tok * 50;
    float v[8];
    float ss = 0.f;
    #pragma unroll
    for (int p = 0; p < 4; ++p) {
        int e = cb * 8 + 2 * p;
        float2 t;
        if (e + 2 <= 50) t = *(const float2*)(src + e);
        else             t = make_float2(0.f, 0.f);
        v[2*p]   = t.x;
        v[2*p+1] = t.y;
        ss = fmaf(t.x, t.x, fmaf(t.y, t.y, ss));
    }
    ss += __shfl_xor(ss, 1, 64);
    ss += __shfl_xor(ss, 2, 64);
    ss += __shfl_xor(ss, 4, 64);
    float rn = __builtin_amdgcn_rsqf(ss);

    unsigned hw[4], lw[4];
    #pragma unroll
    for (int p = 0; p < 4; ++p) {
        float a = v[2*p]   * rn;
        float b = v[2*p+1] * rn;
        unsigned ha = __float_as_uint(a) & 0xFFFF0000u;
        unsigned hb = __float_as_uint(b) & 0xFFFF0000u;
        float la = a - __uint_as_float(ha);
        float lb = b - __uint_as_float(hb);
        hw[p] = (ha >> 16) | hb;
        lw[p] = (__float_as_uint(la) >> 16) | (__float_as_uint(lb) & 0xFFFF0000u);
    }
    int cidx = cb ^ (row & 7);
    hmat[row * 8 + cidx] = make_uint4(hw[0], hw[1], hw[2], hw[3]);
    lmat[row * 8 + cidx] = make_uint4(lw[0], lw[1], lw[2], lw[3]);
}

__global__ __launch_bounds__(256, 4) void knrm_pass_fb(
    const int* __restrict__ q1, const int* __restrict__ d1,
    const int* __restrict__ q2, const int* __restrict__ d2,
    const float* __restrict__ emb, const float* __restrict__ mlp_w,
    float* __restrict__ ws_logit)
{
    __shared__ uint4 qh4[256], ql4[256];
    __shared__ uint4 dh4[256], dl4[256];
    __shared__ float Swk[4][21][16];
    __shared__ float wred[4];

    const int tid  = threadIdx.x;
    const int bx   = blockIdx.x;
    const int b    = bx >> 1;
    const int lane = tid & 63;
    const int wave = tid >> 6;
    const int g    = lane >> 4;

    const int* qidx = ((bx & 1) ? q2 : q1) + b * 32;
    const int* didx = ((bx & 1) ? d2 : d1) + b * 512;

    const int srow = tid >> 3;
    const int scb  = tid & 7;

    stage_row_chunk(emb, qidx[srow], srow, scb, qh4, ql4);
    __syncthreads();

    const int qrow = (wave >> 1) * 16 + (lane & 15);
    short8 Bh0 = frag_ld(qh4, qrow, g);
    short8 Bh1 = frag_ld(qh4, qrow, 4 + g);
    short8 Bl0 = frag_ld(ql4, qrow, g);
    short8 Bl1 = frag_ld(ql4, qrow, 4 + g);

    f32x2 acc2[21];
    #pragma unroll
    for (int k = 0; k < 21; ++k) acc2[k] = (f32x2){0.f, 0.f};

    const int arow = (wave & 1) * 16 + (lane & 15);

    for (int c = 0; c < 16; ++c) {
        if (c) __syncthreads();
        stage_row_chunk(emb, didx[c * 32 + srow], srow, scb, dh4, dl4);
        __syncthreads();

        doc_step(frag_ld(dh4, arow, g), frag_ld(dh4, arow, 4 + g),
                 frag_ld(dl4, arow, g), frag_ld(dl4, arow, 4 + g),
                 Bh0, Bh1, Bl0, Bl1, acc2);
    }
    __syncthreads();

    float acc[21];
    #pragma unroll
    for (int k = 0; k < 21; ++k) {
        float v = acc2[k].x + acc2[k].y;
        v += __shfl_xor(v, 16, 64);
        v += __shfl_xor(v, 32, 64);
        acc[k] = v;
    }
    if (lane < 16) {
        #pragma unroll
        for (int k = 0; k < 21; ++k) Swk[wave][k][lane] = acc[k];
    }
    __syncthreads();

    float local = 0.f;
    for (int p = tid; p < 21 * 32; p += 256) {
        int k = p >> 5, q = p & 31;
        int wp = (q >> 4) * 2;
        float S = Swk[wp][k][q & 15] + Swk[wp + 1][k][q & 15];
        float j = (float)(k - 9);
        float scale = (k < 20) ? fexp2(-0.7213475204444817f * j * j) : 1.0f;
        local += mlp_w[k] * log1pf(S * scale);
    }
    #pragma unroll
    for (int off = 1; off < 64; off <<= 1) local += __shfl_xor(local, off, 64);
    if (lane == 0) wred[wave] = local;
    __syncthreads();
    if (tid == 0)
        ws_logit[bx] = wred[0] + wred[1] + wred[2] + wred[3];
}

// quad=1: P has 4 partials per batch (b*4 + pass*2 + qtile)
// quad=0: P has 2 logits per batch (b*2 + pass)
__global__ void knrm_final_kernel(const float* __restrict__ P,
                                  float* __restrict__ out, int B, int quad)
{
    int i = blockIdx.x * 256 + threadIdx.x;
    if (i < B) {
        float x = quad ? (P[4 * i] + P[4 * i + 1]) - (P[4 * i + 2] + P[4 * i + 3])
                       : P[2 * i] - P[2 * i + 1];
        out[i] = 1.0f / (1.0f + fexp2(-LOG2E * x));
    }
}

extern "C" void kernel_launch(void* const* d_in, const int* in_sizes, int n_in,
                              void* d_out, int out_size, void* d_ws, size_t ws_size,
                              hipStream_t stream) {
    const int*   q1    = (const int*)d_in[0];
    const int*   d1    = (const int*)d_in[1];
    const int*   q2    = (const int*)d_in[2];
    const int*   d2    = (const int*)d_in[3];
    const float* emb   = (const float*)d_in[4];
    const float* mlp_w = (const float*)d_in[5];
    float*       out   = (float*)d_out;

    const int B     = out_size;            // 1024
    const int vocab = in_sizes[4] / 50;    // 100000

    float* ws_part = (float*)d_ws;                        // 4*B floats = 16384 B
    uint4* wse     = (uint4*)((char*)d_ws + 16384);       // prepped embeddings
    size_t need    = 16384 + (size_t)vocab * 256;

    if (ws_size >= need) {
        knrm_prep_kernel<<<dim3((vocab + 31) / 32), dim3(256), 0, stream>>>(emb, wse, vocab);
        knrm_pass_pre<<<dim3(4 * B), dim3(256), 0, stream>>>(
            q1, d1, q2, d2, wse, mlp_w, ws_part);
        knrm_final_kernel<<<dim3((B + 255) / 256), dim3(256), 0, stream>>>(ws_part, out, B, 1);
    } else {
        knrm_pass_fb<<<dim3(2 * B), dim3(256), 0, stream>>>(
            q1, d1, q2, d2, emb, mlp_w, ws_part);
        knrm_final_kernel<<<dim3((B + 255) / 256), dim3(256), 0, stream>>>(ws_part, out, B, 0);
    }
}